// Round 1
// baseline (1271.833 us; speedup 1.0000x reference)
//
#include <hip/hip_runtime.h>

#define N_SEQ 16384
#define T_LEN 16
#define E_DIM 256
#define H_DIM 256
#define G4    1024
#define K_DIM 512
#define B_SAMP 128
#define D_OUT 512
#define V_SIZE 10000

typedef __bf16 bf16x8 __attribute__((ext_vector_type(8)));
typedef float  f32x4  __attribute__((ext_vector_type(4)));
typedef unsigned short u16x8 __attribute__((ext_vector_type(8)));

__device__ __forceinline__ unsigned short f2bf(float x) {
  unsigned int u = __float_as_uint(x);
  u = (u + 0x7fffu + ((u >> 16) & 1u)) >> 16;
  return (unsigned short)u;
}
__device__ __forceinline__ float bf2f(unsigned short v) {
  return __uint_as_float(((unsigned int)v) << 16);
}
__device__ __forceinline__ float sigmoidf_(float x) {
  return 1.0f / (1.0f + __expf(-x));
}

// ---------------- prep kernels ----------------

__global__ __launch_bounds__(256) void k_lens(const int* __restrict__ tok, int* __restrict__ lens) {
  int n = blockIdx.x * 256 + threadIdx.x;
  const int* r = tok + n * T_LEN;
  int c = 0;
#pragma unroll
  for (int t = 0; t < T_LEN; ++t) c += (r[t] != 0);
  lens[n] = c;
}

__global__ __launch_bounds__(256) void k_embcvt(const float* __restrict__ emb, unsigned short* __restrict__ out) {
  int i = blockIdx.x * 256 + threadIdx.x;  // exactly V_SIZE*E_DIM threads
  out[i] = f2bf(emb[i]);
}

// Build per-direction weight buffer WpT[pcol][k] (bf16, row-major [1024][512]):
// pcol = u*128 + q*32 + jj  maps to original gate-row r = q*256 + u*32 + jj,
// k<256 -> W_ih[r][k], k>=256 -> W_hh[r][k-256].
__global__ __launch_bounds__(256) void k_wprep(const float* __restrict__ Wih_f, const float* __restrict__ Whh_f,
                                               const float* __restrict__ Wih_b, const float* __restrict__ Whh_b,
                                               unsigned short* __restrict__ wpt_f, unsigned short* __restrict__ wpt_b) {
  int id = blockIdx.x * 256 + threadIdx.x;  // < 2*1024*512
  int dir = id >> 19;
  int rem = id & ((1 << 19) - 1);
  int pcol = rem >> 9;
  int k = rem & 511;
  int u = pcol >> 7, q = (pcol >> 5) & 3, jj = pcol & 31;
  int r = q * 256 + u * 32 + jj;
  const float* Wih = dir ? Wih_b : Wih_f;
  const float* Whh = dir ? Whh_b : Whh_f;
  float v = (k < 256) ? Wih[r * 256 + k] : Whh[r * 256 + (k - 256)];
  unsigned short* o = dir ? wpt_b : wpt_f;
  o[pcol * 512 + k] = f2bf(v);
}

// ---------------- LSTM step: GEMM + fused cell update ----------------
// Tile: 128 rows x 128 permuted cols (= 32 hidden units x 4 gates), K=512.
// 4 waves; wave w owns rows w*32..w*32+31 (2 row-frags x 8 col-frags of 16x16).

__global__ __launch_bounds__(256, 2)
void k_step(const unsigned short* __restrict__ embbf, const int* __restrict__ tok,
            const int* __restrict__ lens,
            const unsigned short* __restrict__ wpt_f, const unsigned short* __restrict__ wpt_b,
            const float* __restrict__ bias_f, const float* __restrict__ bias_b,
            const unsigned short* __restrict__ hr_f, unsigned short* __restrict__ hw_f,
            const unsigned short* __restrict__ hr_b, unsigned short* __restrict__ hw_b,
            float* __restrict__ c_f, float* __restrict__ c_b,
            int s) {
  const int dir = blockIdx.y;
  const int t = dir ? (T_LEN - 1 - s) : s;
  const unsigned short* wpt = dir ? wpt_b : wpt_f;
  const float* bias = dir ? bias_b : bias_f;
  const unsigned short* hr = dir ? hr_b : hr_f;
  unsigned short* hw = dir ? hw_b : hw_f;
  float* cc = dir ? c_b : c_f;

  const int mblk = blockIdx.x >> 3;
  const int nblk = blockIdx.x & 7;
  const int m0 = mblk * 128;

  __shared__ unsigned short ldsA[128 * 40];  // padded stride 40 (80B) vs 32
  __shared__ unsigned short ldsB[128 * 40];

  const int tid = threadIdx.x;
  const int lane = tid & 63;
  const int w = tid >> 6;

  // staging: 2 threads per row, 16 bf16 (32B) each
  const int srow = tid >> 1;
  const int spart = tid & 1;
  const int atok = tok[(m0 + srow) * T_LEN + t];
  const unsigned short* aev = embbf + (size_t)atok * E_DIM + spart * 16;
  const unsigned short* ahv = hr + (size_t)(m0 + srow) * H_DIM + spart * 16;
  const unsigned short* bsv = wpt + (size_t)(nblk * 128 + srow) * K_DIM + spart * 16;

  f32x4 acc[2][8] = {};

  const int fk = (lane >> 4) * 8;
  const int frow = lane & 15;
  const int aoff0 = (w * 32 + frow) * 40 + fk;
  const int aoff1 = aoff0 + 16 * 40;

  for (int kt = 0; kt < 16; ++kt) {
    const int k0 = kt * 32;
    const unsigned short* as = (k0 < E_DIM) ? (aev + k0) : (ahv + (k0 - E_DIM));
    *(u16x8*)&ldsA[srow * 40 + spart * 16]     = *(const u16x8*)as;
    *(u16x8*)&ldsA[srow * 40 + spart * 16 + 8] = *(const u16x8*)(as + 8);
    *(u16x8*)&ldsB[srow * 40 + spart * 16]     = *(const u16x8*)(bsv + k0);
    *(u16x8*)&ldsB[srow * 40 + spart * 16 + 8] = *(const u16x8*)(bsv + k0 + 8);
    __syncthreads();
    bf16x8 a0 = *(const bf16x8*)&ldsA[aoff0];
    bf16x8 a1 = *(const bf16x8*)&ldsA[aoff1];
#pragma unroll
    for (int fc = 0; fc < 8; ++fc) {
      bf16x8 bb = *(const bf16x8*)&ldsB[(fc * 16 + frow) * 40 + fk];
      acc[0][fc] = __builtin_amdgcn_mfma_f32_16x16x32_bf16(a0, bb, acc[0][fc], 0, 0, 0);
      acc[1][fc] = __builtin_amdgcn_mfma_f32_16x16x32_bf16(a1, bb, acc[1][fc], 0, 0, 0);
    }
    __syncthreads();
  }

  // fused LSTM cell update; lane holds i,f,g,o for same (n, j)
  const int jb = nblk * 32;
#pragma unroll
  for (int fr = 0; fr < 2; ++fr) {
    const int nbase = m0 + w * 32 + fr * 16 + (lane >> 4) * 4;
#pragma unroll
    for (int uf = 0; uf < 2; ++uf) {
      const int j = jb + uf * 16 + frow;
      const float bi = bias[j], bfv = bias[256 + j], bg = bias[512 + j], bo = bias[768 + j];
      f32x4 gi = acc[fr][uf], gf = acc[fr][2 + uf], gg = acc[fr][4 + uf], go = acc[fr][6 + uf];
#pragma unroll
      for (int r = 0; r < 4; ++r) {
        const int n = nbase + r;
        const size_t idx = (size_t)n * H_DIM + j;
        if (t < lens[n]) {
          float iv = sigmoidf_(gi[r] + bi);
          float fv = sigmoidf_(gf[r] + bfv);
          float gv = tanhf(gg[r] + bg);
          float ov = sigmoidf_(go[r] + bo);
          float cn = fv * cc[idx] + iv * gv;
          cc[idx] = cn;
          hw[idx] = f2bf(ov * tanhf(cn));
        } else {
          hw[idx] = hr[idx];  // frozen state carried through ping-pong
        }
      }
    }
  }
}

// ---------------- segment-mean pool (before the linear layer) ----------------

__global__ __launch_bounds__(256) void k_pool(const unsigned short* __restrict__ hf,
                                              const unsigned short* __restrict__ hb,
                                              const int* __restrict__ plen,
                                              float* __restrict__ pooled) {
  const int b = blockIdx.x, tid = threadIdx.x;
  int start = 0;
  for (int i = 0; i < b; ++i) start += plen[i];
  const int cnt = plen[b];
  float s0 = 0.f, s1 = 0.f;
  for (int r = 0; r < cnt; ++r) {
    s0 += bf2f(hf[(size_t)(start + r) * H_DIM + tid]);
    s1 += bf2f(hb[(size_t)(start + r) * H_DIM + tid]);
  }
  float inv = 1.0f / (float)cnt;
  pooled[b * D_OUT + tid] = s0 * inv;
  pooled[b * D_OUT + H_DIM + tid] = s1 * inv;
}

// ---------------- tiny linear (128x512x512) + L2 normalize, f32 ----------------

__global__ __launch_bounds__(256) void k_final(const float* __restrict__ pooled,
                                               const float* __restrict__ W,
                                               const float* __restrict__ bl,
                                               float* __restrict__ out) {
  const int b = blockIdx.x, tid = threadIdx.x;
  __shared__ float pv[512];
  __shared__ float pre[512];
  __shared__ float red[4];
  pv[tid] = pooled[b * 512 + tid];
  pv[tid + 256] = pooled[b * 512 + 256 + tid];
  __syncthreads();
#pragma unroll
  for (int half = 0; half < 2; ++half) {
    const int dd = tid + half * 256;
    const f32x4* wr = (const f32x4*)(W + (size_t)dd * 512);
    const f32x4* pvv = (const f32x4*)pv;
    float s = bl[dd];
#pragma unroll 4
    for (int k4 = 0; k4 < 128; ++k4) {
      f32x4 wv = wr[k4], xv = pvv[k4];
      s += wv[0] * xv[0] + wv[1] * xv[1] + wv[2] * xv[2] + wv[3] * xv[3];
    }
    pre[dd] = s;
  }
  __syncthreads();
  float ss = pre[tid] * pre[tid] + pre[tid + 256] * pre[tid + 256];
#pragma unroll
  for (int off = 32; off > 0; off >>= 1) ss += __shfl_down(ss, off, 64);
  if ((tid & 63) == 0) red[tid >> 6] = ss;
  __syncthreads();
  float tot = red[0] + red[1] + red[2] + red[3];
  float scale = 1.0f / fmaxf(sqrtf(tot), 1e-5f);
  out[b * 512 + tid] = pre[tid] * scale;
  out[b * 512 + 256 + tid] = pre[tid + 256] * scale;
}

// ---------------- launch ----------------

extern "C" void kernel_launch(void* const* d_in, const int* in_sizes, int n_in,
                              void* d_out, int out_size, void* d_ws, size_t ws_size,
                              hipStream_t stream) {
  const int* tok    = (const int*)d_in[0];
  const int* plen   = (const int*)d_in[1];
  const float* emb  = (const float*)d_in[2];
  const float* Wih_f = (const float*)d_in[3];
  const float* Whh_f = (const float*)d_in[4];
  const float* b_f   = (const float*)d_in[5];
  const float* Wih_b = (const float*)d_in[6];
  const float* Whh_b = (const float*)d_in[7];
  const float* b_b   = (const float*)d_in[8];
  const float* Wlin  = (const float*)d_in[9];
  const float* blin  = (const float*)d_in[10];
  float* out = (float*)d_out;

  char* ws = (char*)d_ws;
  size_t off = 0;
  auto alloc = [&](size_t bytes) {
    void* p = ws + off;
    off = (off + bytes + 255) & ~(size_t)255;
    return p;
  };
  unsigned short* embbf = (unsigned short*)alloc((size_t)V_SIZE * E_DIM * 2);
  unsigned short* wptf  = (unsigned short*)alloc((size_t)G4 * K_DIM * 2);
  unsigned short* wptb  = (unsigned short*)alloc((size_t)G4 * K_DIM * 2);
  int* lens             = (int*)alloc((size_t)N_SEQ * 4);
  unsigned short* h0f   = (unsigned short*)alloc((size_t)N_SEQ * H_DIM * 2);
  unsigned short* h1f   = (unsigned short*)alloc((size_t)N_SEQ * H_DIM * 2);
  unsigned short* h0b   = (unsigned short*)alloc((size_t)N_SEQ * H_DIM * 2);
  unsigned short* h1b   = (unsigned short*)alloc((size_t)N_SEQ * H_DIM * 2);
  float* cf             = (float*)alloc((size_t)N_SEQ * H_DIM * 4);
  float* cb             = (float*)alloc((size_t)N_SEQ * H_DIM * 4);
  float* pooled         = (float*)alloc((size_t)B_SAMP * D_OUT * 4);

  hipMemsetAsync(h0f, 0, (size_t)N_SEQ * H_DIM * 2, stream);
  hipMemsetAsync(h0b, 0, (size_t)N_SEQ * H_DIM * 2, stream);
  hipMemsetAsync(cf, 0, (size_t)N_SEQ * H_DIM * 4, stream);
  hipMemsetAsync(cb, 0, (size_t)N_SEQ * H_DIM * 4, stream);

  k_lens<<<N_SEQ / 256, 256, 0, stream>>>(tok, lens);
  k_embcvt<<<(V_SIZE * E_DIM) / 256, 256, 0, stream>>>(emb, embbf);
  k_wprep<<<(2 * G4 * K_DIM) / 256, 256, 0, stream>>>(Wih_f, Whh_f, Wih_b, Whh_b, wptf, wptb);

  dim3 grid(1024, 2);
  for (int s = 0; s < T_LEN; ++s) {
    const unsigned short* hrf = (s & 1) ? h1f : h0f;
    unsigned short* hwf       = (s & 1) ? h0f : h1f;
    const unsigned short* hrb = (s & 1) ? h1b : h0b;
    unsigned short* hwb       = (s & 1) ? h0b : h1b;
    k_step<<<grid, 256, 0, stream>>>(embbf, tok, lens, wptf, wptb, b_f, b_b,
                                     hrf, hwf, hrb, hwb, cf, cb, s);
  }
  // after s=15 (odd), final h is in h0f / h0b
  k_pool<<<B_SAMP, 256, 0, stream>>>(h0f, h0b, plen, pooled);
  k_final<<<B_SAMP, 256, 0, stream>>>(pooled, Wlin, blin, out);
}

// Round 2
// 1015.182 us; speedup vs baseline: 1.2528x; 1.2528x over previous
//
#include <hip/hip_runtime.h>
#include <stdint.h>

#define N_SEQ 16384
#define T_LEN 16
#define E_DIM 256
#define H_DIM 256
#define K_DIM 512
#define B_SAMP 128
#define V_SIZE 10000

typedef __bf16 bf16x8 __attribute__((ext_vector_type(8)));
typedef float  f32x4  __attribute__((ext_vector_type(4)));

__device__ __forceinline__ unsigned short f2bf(float x) {
  unsigned int u = __float_as_uint(x);
  u = (u + 0x7fffu + ((u >> 16) & 1u)) >> 16;
  return (unsigned short)u;
}
__device__ __forceinline__ float bf2f(unsigned short v) {
  return __uint_as_float(((unsigned int)v) << 16);
}
__device__ __forceinline__ float sigmoidf_(float x) {
  return 1.0f / (1.0f + __expf(-x));
}
__device__ __forceinline__ void glds16(const void* g, const void* l) {
  __builtin_amdgcn_global_load_lds(
      (const __attribute__((address_space(1))) unsigned int*)g,
      (__attribute__((address_space(3))) unsigned int*)l, 16, 0, 0);
}

// ---------------- prep kernels ----------------

__global__ __launch_bounds__(256) void k_lens(const int* __restrict__ tok, int* __restrict__ lens) {
  int n = blockIdx.x * 256 + threadIdx.x;
  const int* r = tok + n * T_LEN;
  int c = 0;
#pragma unroll
  for (int t = 0; t < T_LEN; ++t) c += (r[t] != 0);
  lens[n] = c;
}

__global__ __launch_bounds__(256) void k_embcvt(const float* __restrict__ emb, unsigned short* __restrict__ out) {
  int i = blockIdx.x * 256 + threadIdx.x;
  out[i] = f2bf(emb[i]);
}

// Permuted weights: wpt[p][k], p = nb*256 + wc*64 + q*16 + jj  <->
// gate-row r = q*256 + (nb*64 + wc*16 + jj);  k<256 -> W_ih[r][k], else W_hh[r][k-256].
__global__ __launch_bounds__(256) void k_wprep(const float* __restrict__ Wih_f, const float* __restrict__ Whh_f,
                                               const float* __restrict__ Wih_b, const float* __restrict__ Whh_b,
                                               unsigned short* __restrict__ wpt_f, unsigned short* __restrict__ wpt_b) {
  int id = blockIdx.x * 256 + threadIdx.x;  // < 2*1024*512
  int dir = id >> 19;
  int rem = id & ((1 << 19) - 1);
  int p = rem >> 9;
  int k = rem & 511;
  int nb = p >> 8, wc = (p >> 6) & 3, q = (p >> 4) & 3, jj = p & 15;
  int r = q * 256 + nb * 64 + wc * 16 + jj;
  const float* Wih = dir ? Wih_b : Wih_f;
  const float* Whh = dir ? Whh_b : Whh_f;
  float v = (k < 256) ? Wih[r * 256 + k] : Whh[r * 256 + (k - 256)];
  unsigned short* o = dir ? wpt_b : wpt_f;
  o[p * 512 + k] = f2bf(v);
}

// ---------------- LSTM step: GEMM + fused cell update ----------------
// 512 threads (8 waves: wr=w>>2, wc=w&3). Block tile 128 rows x 256 pcols, K=512 in
// 8 chunks of 64. Wave tile 64x64 = 4x4 frags of 16x16x32. Staging via
// global_load_lds(16B) into XOR-swizzled [row][chunk^ (row&7)] layout (128B rows).

__global__ __launch_bounds__(512, 4)
void k_step(const unsigned short* __restrict__ embbf, const int* __restrict__ tok,
            const int* __restrict__ lens,
            const unsigned short* __restrict__ wpt_f, const unsigned short* __restrict__ wpt_b,
            const float* __restrict__ bias_f, const float* __restrict__ bias_b,
            const unsigned short* __restrict__ hr_f, unsigned short* __restrict__ hw_f,
            const unsigned short* __restrict__ hr_b, unsigned short* __restrict__ hw_b,
            float* __restrict__ c_f, float* __restrict__ c_b,
            int s) {
  const int dir = blockIdx.y;
  const int t = dir ? (T_LEN - 1 - s) : s;
  const unsigned short* wpt = dir ? wpt_b : wpt_f;
  const float* bias = dir ? bias_b : bias_f;
  const unsigned short* hr = dir ? hr_b : hr_f;
  unsigned short* hw = dir ? hw_b : hw_f;
  float* cc = dir ? c_b : c_f;

  const int mblk = blockIdx.x >> 2;
  const int nblk = blockIdx.x & 3;
  const int m0 = mblk * 128;

  __shared__ __align__(128) unsigned char ldsA[128 * 128];  // 16 KB
  __shared__ __align__(128) unsigned char ldsB[256 * 128];  // 32 KB

  const int tid = threadIdx.x;
  const int lane = tid & 63;
  const int w = tid >> 6;
  const int wr = w >> 2;
  const int wc = w & 3;

  // ---- staging address precompute (element offsets, fixed per thread) ----
  const int l8 = lane >> 3;        // sub-row within 8-row group
  const int l7 = lane & 7;         // chunk slot in LDS
  const int arow0 = 16 * w + l8;
  const int arow1 = arow0 + 8;
  const int ach0 = l7 ^ (arow0 & 7);
  const int ach1 = l7 ^ (arow1 & 7);
  const unsigned aoffE0 = (unsigned)tok[(m0 + arow0) * T_LEN + t] * E_DIM + ach0 * 8;
  const unsigned aoffE1 = (unsigned)tok[(m0 + arow1) * T_LEN + t] * E_DIM + ach1 * 8;
  const unsigned aoffH0 = (unsigned)(m0 + arow0) * H_DIM + ach0 * 8;
  const unsigned aoffH1 = (unsigned)(m0 + arow1) * H_DIM + ach1 * 8;
  unsigned boff[4];
#pragma unroll
  for (int j = 0; j < 4; ++j) {
    const int brow = 32 * w + 8 * j + l8;
    const int bch = l7 ^ (brow & 7);
    boff[j] = (unsigned)(nblk * 256 + brow) * K_DIM + bch * 8;
  }

  f32x4 acc[4][4] = {};
  const int frow = lane & 15;
  const int fkq = lane >> 4;  // 0..3

  for (int kt = 0; kt < 8; ++kt) {
    const int k0 = kt * 64;
    if (kt < 4) {
      glds16(embbf + aoffE0 + k0, &ldsA[(16 * w) * 128]);
      glds16(embbf + aoffE1 + k0, &ldsA[(16 * w + 8) * 128]);
    } else {
      glds16(hr + aoffH0 + (k0 - E_DIM), &ldsA[(16 * w) * 128]);
      glds16(hr + aoffH1 + (k0 - E_DIM), &ldsA[(16 * w + 8) * 128]);
    }
#pragma unroll
    for (int j = 0; j < 4; ++j)
      glds16(wpt + boff[j] + k0, &ldsB[(32 * w + 8 * j) * 128]);
    __syncthreads();  // drains vmcnt (compiler emits full waitcnt before barrier)
#pragma unroll
    for (int ksub = 0; ksub < 2; ++ksub) {
      bf16x8 av[4], bv[4];
#pragma unroll
      for (int fr = 0; fr < 4; ++fr) {
        const int row = wr * 64 + fr * 16 + frow;
        const int ch = (ksub * 4 + fkq) ^ (row & 7);
        av[fr] = *(const bf16x8*)&ldsA[row * 128 + ch * 16];
      }
#pragma unroll
      for (int fc = 0; fc < 4; ++fc) {
        const int row = wc * 64 + fc * 16 + frow;
        const int ch = (ksub * 4 + fkq) ^ (row & 7);
        bv[fc] = *(const bf16x8*)&ldsB[row * 128 + ch * 16];
      }
#pragma unroll
      for (int fr = 0; fr < 4; ++fr)
#pragma unroll
        for (int fc = 0; fc < 4; ++fc)
          acc[fr][fc] = __builtin_amdgcn_mfma_f32_16x16x32_bf16(av[fr], bv[fc], acc[fr][fc], 0, 0, 0);
    }
    __syncthreads();
  }

  // ---- fused LSTM cell update: fc = gate (i,f,g,o) for hidden unit j ----
  const int j = nblk * 64 + wc * 16 + frow;
  const float bi = bias[j], bfv = bias[256 + j], bg = bias[512 + j], bo = bias[768 + j];
#pragma unroll
  for (int fr = 0; fr < 4; ++fr) {
    const int nbase = m0 + wr * 64 + fr * 16 + fkq * 4;
    const int4 ln4 = *(const int4*)&lens[nbase];
    const f32x4 gi = acc[fr][0], gf = acc[fr][1], gg = acc[fr][2], go = acc[fr][3];
#pragma unroll
    for (int r = 0; r < 4; ++r) {
      const int n = nbase + r;
      const int ln = (r == 0) ? ln4.x : (r == 1) ? ln4.y : (r == 2) ? ln4.z : ln4.w;
      const size_t idx = (size_t)n * H_DIM + j;
      if (t < ln) {
        float iv = sigmoidf_(gi[r] + bi);
        float fv = sigmoidf_(gf[r] + bfv);
        float gv = tanhf(gg[r] + bg);
        float ov = sigmoidf_(go[r] + bo);
        float cn = fv * cc[idx] + iv * gv;
        cc[idx] = cn;
        hw[idx] = f2bf(ov * tanhf(cn));
      } else {
        hw[idx] = hr[idx];  // frozen state carried through ping-pong
      }
    }
  }
}

// ---------------- segment-mean pool (before the linear layer) ----------------

__global__ __launch_bounds__(256) void k_pool(const unsigned short* __restrict__ hf,
                                              const unsigned short* __restrict__ hb,
                                              const int* __restrict__ plen,
                                              float* __restrict__ pooled) {
  const int b = blockIdx.x, tid = threadIdx.x;
  int start = 0;
  for (int i = 0; i < b; ++i) start += plen[i];
  const int cnt = plen[b];
  float s0 = 0.f, s1 = 0.f;
  for (int r = 0; r < cnt; ++r) {
    s0 += bf2f(hf[(size_t)(start + r) * H_DIM + tid]);
    s1 += bf2f(hb[(size_t)(start + r) * H_DIM + tid]);
  }
  float inv = 1.0f / (float)cnt;
  pooled[b * 512 + tid] = s0 * inv;
  pooled[b * 512 + H_DIM + tid] = s1 * inv;
}

// ---------------- tiny linear (128x512x512) + L2 normalize, f32 ----------------

__global__ __launch_bounds__(256) void k_final(const float* __restrict__ pooled,
                                               const float* __restrict__ W,
                                               const float* __restrict__ bl,
                                               float* __restrict__ out) {
  const int b = blockIdx.x, tid = threadIdx.x;
  __shared__ float pv[512];
  __shared__ float pre[512];
  __shared__ float red[4];
  pv[tid] = pooled[b * 512 + tid];
  pv[tid + 256] = pooled[b * 512 + 256 + tid];
  __syncthreads();
#pragma unroll
  for (int half = 0; half < 2; ++half) {
    const int dd = tid + half * 256;
    const f32x4* wr = (const f32x4*)(W + (size_t)dd * 512);
    const f32x4* pvv = (const f32x4*)pv;
    float s = bl[dd];
#pragma unroll 4
    for (int k4 = 0; k4 < 128; ++k4) {
      f32x4 wv = wr[k4], xv = pvv[k4];
      s += wv[0] * xv[0] + wv[1] * xv[1] + wv[2] * xv[2] + wv[3] * xv[3];
    }
    pre[dd] = s;
  }
  __syncthreads();
  float ss = pre[tid] * pre[tid] + pre[tid + 256] * pre[tid + 256];
#pragma unroll
  for (int off = 32; off > 0; off >>= 1) ss += __shfl_down(ss, off, 64);
  if ((tid & 63) == 0) red[tid >> 6] = ss;
  __syncthreads();
  float tot = red[0] + red[1] + red[2] + red[3];
  float scale = 1.0f / fmaxf(sqrtf(tot), 1e-5f);
  out[b * 512 + tid] = pre[tid] * scale;
  out[b * 512 + 256 + tid] = pre[tid + 256] * scale;
}

// ---------------- launch ----------------

extern "C" void kernel_launch(void* const* d_in, const int* in_sizes, int n_in,
                              void* d_out, int out_size, void* d_ws, size_t ws_size,
                              hipStream_t stream) {
  const int* tok    = (const int*)d_in[0];
  const int* plen   = (const int*)d_in[1];
  const float* emb  = (const float*)d_in[2];
  const float* Wih_f = (const float*)d_in[3];
  const float* Whh_f = (const float*)d_in[4];
  const float* b_f   = (const float*)d_in[5];
  const float* Wih_b = (const float*)d_in[6];
  const float* Whh_b = (const float*)d_in[7];
  const float* b_b   = (const float*)d_in[8];
  const float* Wlin  = (const float*)d_in[9];
  const float* blin  = (const float*)d_in[10];
  float* out = (float*)d_out;

  char* ws = (char*)d_ws;
  size_t off = 0;
  auto alloc = [&](size_t bytes) {
    void* p = ws + off;
    off = (off + bytes + 255) & ~(size_t)255;
    return p;
  };
  unsigned short* embbf = (unsigned short*)alloc((size_t)V_SIZE * E_DIM * 2);
  unsigned short* wptf  = (unsigned short*)alloc((size_t)1024 * K_DIM * 2);
  unsigned short* wptb  = (unsigned short*)alloc((size_t)1024 * K_DIM * 2);
  int* lens             = (int*)alloc((size_t)N_SEQ * 4);
  unsigned short* h0f   = (unsigned short*)alloc((size_t)N_SEQ * H_DIM * 2);
  unsigned short* h1f   = (unsigned short*)alloc((size_t)N_SEQ * H_DIM * 2);
  unsigned short* h0b   = (unsigned short*)alloc((size_t)N_SEQ * H_DIM * 2);
  unsigned short* h1b   = (unsigned short*)alloc((size_t)N_SEQ * H_DIM * 2);
  float* cf             = (float*)alloc((size_t)N_SEQ * H_DIM * 4);
  float* cb             = (float*)alloc((size_t)N_SEQ * H_DIM * 4);
  float* pooled         = (float*)alloc((size_t)B_SAMP * 512 * 4);

  hipMemsetAsync(h0f, 0, (size_t)N_SEQ * H_DIM * 2, stream);
  hipMemsetAsync(h0b, 0, (size_t)N_SEQ * H_DIM * 2, stream);
  hipMemsetAsync(cf, 0, (size_t)N_SEQ * H_DIM * 4, stream);
  hipMemsetAsync(cb, 0, (size_t)N_SEQ * H_DIM * 4, stream);

  k_lens<<<N_SEQ / 256, 256, 0, stream>>>(tok, lens);
  k_embcvt<<<(V_SIZE * E_DIM) / 256, 256, 0, stream>>>(emb, embbf);
  k_wprep<<<(2 * 1024 * K_DIM) / 256, 256, 0, stream>>>(Wih_f, Whh_f, Wih_b, Whh_b, wptf, wptb);

  dim3 grid(512, 2);
  for (int s = 0; s < T_LEN; ++s) {
    const unsigned short* hrf = (s & 1) ? h1f : h0f;
    unsigned short* hwf       = (s & 1) ? h0f : h1f;
    const unsigned short* hrb = (s & 1) ? h1b : h0b;
    unsigned short* hwb       = (s & 1) ? h0b : h1b;
    k_step<<<grid, 512, 0, stream>>>(embbf, tok, lens, wptf, wptb, b_f, b_b,
                                     hrf, hwf, hrb, hwb, cf, cb, s);
  }
  // after s=15 (odd), final h is in h0f / h0b
  k_pool<<<B_SAMP, 256, 0, stream>>>(h0f, h0b, plen, pooled);
  k_final<<<B_SAMP, 256, 0, stream>>>(pooled, Wlin, blin, out);
}

// Round 3
// 943.617 us; speedup vs baseline: 1.3478x; 1.0758x over previous
//
#include <hip/hip_runtime.h>
#include <stdint.h>

#define N_SEQ 16384
#define T_LEN 16
#define E_DIM 256
#define H_DIM 256
#define K_DIM 512
#define B_SAMP 128
#define V_SIZE 10000

typedef __bf16 bf16x8 __attribute__((ext_vector_type(8)));
typedef float  f32x4  __attribute__((ext_vector_type(4)));

__device__ __forceinline__ unsigned short f2bf(float x) {
  unsigned int u = __float_as_uint(x);
  u = (u + 0x7fffu + ((u >> 16) & 1u)) >> 16;
  return (unsigned short)u;
}
__device__ __forceinline__ float bf2f(unsigned short v) {
  return __uint_as_float(((unsigned int)v) << 16);
}
__device__ __forceinline__ float sigmoidf_(float x) {
  return 1.0f / (1.0f + __expf(-x));
}
__device__ __forceinline__ void glds16(const void* g, const void* l) {
  __builtin_amdgcn_global_load_lds(
      (const __attribute__((address_space(1))) unsigned int*)g,
      (__attribute__((address_space(3))) unsigned int*)l, 16, 0, 0);
}

// ---------------- prep kernels ----------------

__global__ __launch_bounds__(256) void k_lens(const int* __restrict__ tok, int* __restrict__ lens) {
  int n = blockIdx.x * 256 + threadIdx.x;
  const int* r = tok + n * T_LEN;
  int c = 0;
#pragma unroll
  for (int t = 0; t < T_LEN; ++t) c += (r[t] != 0);
  lens[n] = c;
}

__global__ __launch_bounds__(256) void k_hist(const int* __restrict__ lens, int* __restrict__ hist) {
  __shared__ int lh[17];
  if (threadIdx.x < 17) lh[threadIdx.x] = 0;
  __syncthreads();
  atomicAdd(&lh[lens[blockIdx.x * 256 + threadIdx.x]], 1);
  __syncthreads();
  if (threadIdx.x < 17) atomicAdd(&hist[threadIdx.x], lh[threadIdx.x]);
}

// descending-length bucket starts + per-step processed counts cnts[t] = count(len >= t)
__global__ void k_offsets(const int* __restrict__ hist, int* __restrict__ cursor, int* __restrict__ cnts) {
  if (threadIdx.x == 0) {
    int off = 0;
    for (int l = 16; l >= 0; --l) { cursor[l] = off; off += hist[l]; }
    for (int t = 0; t < 16; ++t) {
      int c = 0;
      for (int l = t; l <= 16; ++l) c += hist[l];
      cnts[t] = c;
    }
  }
}

__global__ __launch_bounds__(256) void k_scatter(const int* __restrict__ lens, int* __restrict__ cursor,
                                                 int* __restrict__ perm, int* __restrict__ pinv,
                                                 int* __restrict__ plens) {
  int n = blockIdx.x * 256 + threadIdx.x;
  int l = lens[n];
  int pos = atomicAdd(&cursor[l], 1);
  perm[pos] = n;
  pinv[n] = pos;
  plens[pos] = l;
}

__global__ __launch_bounds__(256) void k_embcvt(const float* __restrict__ emb, unsigned short* __restrict__ out) {
  int i = blockIdx.x * 256 + threadIdx.x;
  out[i] = f2bf(emb[i]);
}

// Permuted weights: wpt[p][k], p = nb*256 + wc*64 + q*16 + jj  <->
// gate-row r = q*256 + (nb*64 + wc*16 + jj);  k<256 -> W_ih[r][k], else W_hh[r][k-256].
__global__ __launch_bounds__(256) void k_wprep(const float* __restrict__ Wih_f, const float* __restrict__ Whh_f,
                                               const float* __restrict__ Wih_b, const float* __restrict__ Whh_b,
                                               unsigned short* __restrict__ wpt_f, unsigned short* __restrict__ wpt_b) {
  int id = blockIdx.x * 256 + threadIdx.x;  // < 2*1024*512
  int dir = id >> 19;
  int rem = id & ((1 << 19) - 1);
  int p = rem >> 9;
  int k = rem & 511;
  int nb = p >> 8, wc = (p >> 6) & 3, q = (p >> 4) & 3, jj = p & 15;
  int r = q * 256 + nb * 64 + wc * 16 + jj;
  const float* Wih = dir ? Wih_b : Wih_f;
  const float* Whh = dir ? Whh_b : Whh_f;
  float v = (k < 256) ? Wih[r * 256 + k] : Whh[r * 256 + (k - 256)];
  unsigned short* o = dir ? wpt_b : wpt_f;
  o[p * 512 + k] = f2bf(v);
}

// ---------------- LSTM step: GEMM + fused cell update ----------------
// Rows are length-sorted (descending); h/c/plens stored in permuted order.
// Active prefix per (dir, s): cnt = cnts[dir ? 15-s : s]; blocks past it exit.
// 512 threads (8 waves). Block tile 128 rows x 256 pcols, K=512 in 8 chunks of 64.
// Wave tile 64x64 = 4x4 frags of 16x16x32. global_load_lds(16B) staging into
// XOR-swizzled [row][chunk ^ (row&7)] layout (128B rows) -> conflict-free ds_read_b128.

__global__ __launch_bounds__(512, 4)
void k_step(const unsigned short* __restrict__ embbf, const int* __restrict__ tok,
            const int* __restrict__ perm, const int* __restrict__ plens,
            const int* __restrict__ cnts,
            const unsigned short* __restrict__ wpt_f, const unsigned short* __restrict__ wpt_b,
            const float* __restrict__ bias_f, const float* __restrict__ bias_b,
            const unsigned short* __restrict__ hr_f, unsigned short* __restrict__ hw_f,
            const unsigned short* __restrict__ hr_b, unsigned short* __restrict__ hw_b,
            float* __restrict__ c_f, float* __restrict__ c_b,
            int s) {
  const int dir = blockIdx.y;
  const int t = dir ? (T_LEN - 1 - s) : s;
  const int mblk = blockIdx.x >> 2;
  const int m0 = mblk * 128;
  const int cnt = cnts[dir ? (15 - s) : s];
  if (m0 >= cnt) return;  // length-sorted: rows past prefix are frozen in both buffers

  const int nblk = blockIdx.x & 3;
  const unsigned short* wpt = dir ? wpt_b : wpt_f;
  const float* bias = dir ? bias_b : bias_f;
  const unsigned short* hr = dir ? hr_b : hr_f;
  unsigned short* hw = dir ? hw_b : hw_f;
  float* cc = dir ? c_b : c_f;

  __shared__ __align__(128) unsigned char ldsA[128 * 128];  // 16 KB
  __shared__ __align__(128) unsigned char ldsB[256 * 128];  // 32 KB

  const int tid = threadIdx.x;
  const int lane = tid & 63;
  const int w = tid >> 6;
  const int wr = w >> 2;
  const int wc = w & 3;

  // ---- staging address precompute (element offsets, fixed per thread) ----
  const int l8 = lane >> 3;        // sub-row within 8-row group
  const int l7 = lane & 7;         // chunk slot in LDS
  const int arow0 = 16 * w + l8;
  const int arow1 = arow0 + 8;
  const int ach0 = l7 ^ (arow0 & 7);
  const int ach1 = l7 ^ (arow1 & 7);
  const int pn0 = perm[m0 + arow0];
  const int pn1 = perm[m0 + arow1];
  const unsigned aoffE0 = (unsigned)tok[pn0 * T_LEN + t] * E_DIM + ach0 * 8;
  const unsigned aoffE1 = (unsigned)tok[pn1 * T_LEN + t] * E_DIM + ach1 * 8;
  const unsigned aoffH0 = (unsigned)(m0 + arow0) * H_DIM + ach0 * 8;
  const unsigned aoffH1 = (unsigned)(m0 + arow1) * H_DIM + ach1 * 8;
  unsigned boff[4];
#pragma unroll
  for (int j = 0; j < 4; ++j) {
    const int brow = 32 * w + 8 * j + l8;
    const int bch = l7 ^ (brow & 7);
    boff[j] = (unsigned)(nblk * 256 + brow) * K_DIM + bch * 8;
  }

  f32x4 acc[4][4] = {};
  const int frow = lane & 15;
  const int fkq = lane >> 4;  // 0..3

  for (int kt = 0; kt < 8; ++kt) {
    const int k0 = kt * 64;
    if (kt < 4) {
      glds16(embbf + aoffE0 + k0, &ldsA[(16 * w) * 128]);
      glds16(embbf + aoffE1 + k0, &ldsA[(16 * w + 8) * 128]);
    } else {
      glds16(hr + aoffH0 + (k0 - E_DIM), &ldsA[(16 * w) * 128]);
      glds16(hr + aoffH1 + (k0 - E_DIM), &ldsA[(16 * w + 8) * 128]);
    }
#pragma unroll
    for (int j = 0; j < 4; ++j)
      glds16(wpt + boff[j] + k0, &ldsB[(32 * w + 8 * j) * 128]);
    __syncthreads();
#pragma unroll
    for (int ksub = 0; ksub < 2; ++ksub) {
      bf16x8 av[4], bv[4];
#pragma unroll
      for (int fr = 0; fr < 4; ++fr) {
        const int row = wr * 64 + fr * 16 + frow;
        const int ch = (ksub * 4 + fkq) ^ (row & 7);
        av[fr] = *(const bf16x8*)&ldsA[row * 128 + ch * 16];
      }
#pragma unroll
      for (int fc = 0; fc < 4; ++fc) {
        const int row = wc * 64 + fc * 16 + frow;
        const int ch = (ksub * 4 + fkq) ^ (row & 7);
        bv[fc] = *(const bf16x8*)&ldsB[row * 128 + ch * 16];
      }
#pragma unroll
      for (int fr = 0; fr < 4; ++fr)
#pragma unroll
        for (int fc = 0; fc < 4; ++fc)
          acc[fr][fc] = __builtin_amdgcn_mfma_f32_16x16x32_bf16(av[fr], bv[fc], acc[fr][fc], 0, 0, 0);
    }
    __syncthreads();
  }

  // ---- fused LSTM cell update: fc = gate (i,f,g,o) for hidden unit j ----
  const int j = nblk * 64 + wc * 16 + frow;
  const float bi = bias[j], bfv = bias[256 + j], bg = bias[512 + j], bo = bias[768 + j];
#pragma unroll
  for (int fr = 0; fr < 4; ++fr) {
    const int nbase = m0 + wr * 64 + fr * 16 + fkq * 4;
    const int4 ln4 = *(const int4*)&plens[nbase];
    const f32x4 gi = acc[fr][0], gf = acc[fr][1], gg = acc[fr][2], go = acc[fr][3];
#pragma unroll
    for (int r = 0; r < 4; ++r) {
      const int n = nbase + r;
      const int ln = (r == 0) ? ln4.x : (r == 1) ? ln4.y : (r == 2) ? ln4.z : ln4.w;
      const size_t idx = (size_t)n * H_DIM + j;
      if (t < ln) {
        float iv = sigmoidf_(gi[r] + bi);
        float fv = sigmoidf_(gf[r] + bfv);
        float gv = tanhf(gg[r] + bg);
        float ov = sigmoidf_(go[r] + bo);
        float cn = fv * cc[idx] + iv * gv;
        cc[idx] = cn;
        hw[idx] = f2bf(ov * tanhf(cn));
      } else {
        hw[idx] = hr[idx];  // buffer-sync copy; idempotent for long-frozen rows
      }
    }
  }
}

// ---------------- segment-mean pool (before the linear layer) ----------------

__global__ __launch_bounds__(256) void k_pool(const unsigned short* __restrict__ hf,
                                              const unsigned short* __restrict__ hb,
                                              const int* __restrict__ pinv,
                                              const int* __restrict__ plen,
                                              float* __restrict__ pooled) {
  const int b = blockIdx.x, tid = threadIdx.x;
  int start = 0;
  for (int i = 0; i < b; ++i) start += plen[i];
  const int cnt = plen[b];
  float s0 = 0.f, s1 = 0.f;
  for (int r = 0; r < cnt; ++r) {
    const size_t pr = (size_t)pinv[start + r];
    s0 += bf2f(hf[pr * H_DIM + tid]);
    s1 += bf2f(hb[pr * H_DIM + tid]);
  }
  float inv = 1.0f / (float)cnt;
  pooled[b * 512 + tid] = s0 * inv;
  pooled[b * 512 + H_DIM + tid] = s1 * inv;
}

// ---------------- tiny linear (128x512x512) + L2 normalize, f32 ----------------

__global__ __launch_bounds__(256) void k_final(const float* __restrict__ pooled,
                                               const float* __restrict__ W,
                                               const float* __restrict__ bl,
                                               float* __restrict__ out) {
  const int b = blockIdx.x, tid = threadIdx.x;
  __shared__ float pv[512];
  __shared__ float pre[512];
  __shared__ float red[4];
  pv[tid] = pooled[b * 512 + tid];
  pv[tid + 256] = pooled[b * 512 + 256 + tid];
  __syncthreads();
#pragma unroll
  for (int half = 0; half < 2; ++half) {
    const int dd = tid + half * 256;
    const f32x4* wr = (const f32x4*)(W + (size_t)dd * 512);
    const f32x4* pvv = (const f32x4*)pv;
    float s = bl[dd];
#pragma unroll 4
    for (int k4 = 0; k4 < 128; ++k4) {
      f32x4 wv = wr[k4], xv = pvv[k4];
      s += wv[0] * xv[0] + wv[1] * xv[1] + wv[2] * xv[2] + wv[3] * xv[3];
    }
    pre[dd] = s;
  }
  __syncthreads();
  float ss = pre[tid] * pre[tid] + pre[tid + 256] * pre[tid + 256];
#pragma unroll
  for (int off = 32; off > 0; off >>= 1) ss += __shfl_down(ss, off, 64);
  if ((tid & 63) == 0) red[tid >> 6] = ss;
  __syncthreads();
  float tot = red[0] + red[1] + red[2] + red[3];
  float scale = 1.0f / fmaxf(sqrtf(tot), 1e-5f);
  out[b * 512 + tid] = pre[tid] * scale;
  out[b * 512 + 256 + tid] = pre[tid + 256] * scale;
}

// ---------------- launch ----------------

extern "C" void kernel_launch(void* const* d_in, const int* in_sizes, int n_in,
                              void* d_out, int out_size, void* d_ws, size_t ws_size,
                              hipStream_t stream) {
  const int* tok    = (const int*)d_in[0];
  const int* plen   = (const int*)d_in[1];
  const float* emb  = (const float*)d_in[2];
  const float* Wih_f = (const float*)d_in[3];
  const float* Whh_f = (const float*)d_in[4];
  const float* b_f   = (const float*)d_in[5];
  const float* Wih_b = (const float*)d_in[6];
  const float* Whh_b = (const float*)d_in[7];
  const float* b_b   = (const float*)d_in[8];
  const float* Wlin  = (const float*)d_in[9];
  const float* blin  = (const float*)d_in[10];
  float* out = (float*)d_out;

  char* ws = (char*)d_ws;
  size_t off = 0;
  auto alloc = [&](size_t bytes) {
    void* p = ws + off;
    off = (off + bytes + 255) & ~(size_t)255;
    return p;
  };
  unsigned short* embbf = (unsigned short*)alloc((size_t)V_SIZE * E_DIM * 2);
  unsigned short* wptf  = (unsigned short*)alloc((size_t)1024 * K_DIM * 2);
  unsigned short* wptb  = (unsigned short*)alloc((size_t)1024 * K_DIM * 2);
  int* lens             = (int*)alloc((size_t)N_SEQ * 4);
  int* perm             = (int*)alloc((size_t)N_SEQ * 4);
  int* pinv             = (int*)alloc((size_t)N_SEQ * 4);
  int* plens            = (int*)alloc((size_t)N_SEQ * 4);
  int* hist             = (int*)alloc(17 * 4);
  int* cursor           = (int*)alloc(17 * 4);
  int* cnts             = (int*)alloc(16 * 4);
  unsigned short* h0f   = (unsigned short*)alloc((size_t)N_SEQ * H_DIM * 2);
  unsigned short* h1f   = (unsigned short*)alloc((size_t)N_SEQ * H_DIM * 2);
  unsigned short* h0b   = (unsigned short*)alloc((size_t)N_SEQ * H_DIM * 2);
  unsigned short* h1b   = (unsigned short*)alloc((size_t)N_SEQ * H_DIM * 2);
  float* cf             = (float*)alloc((size_t)N_SEQ * H_DIM * 4);
  float* cb             = (float*)alloc((size_t)N_SEQ * H_DIM * 4);
  float* pooled         = (float*)alloc((size_t)B_SAMP * 512 * 4);

  hipMemsetAsync(hist, 0, 17 * 4, stream);
  hipMemsetAsync(h0f, 0, (size_t)N_SEQ * H_DIM * 2, stream);
  hipMemsetAsync(h0b, 0, (size_t)N_SEQ * H_DIM * 2, stream);
  hipMemsetAsync(h1f, 0, (size_t)N_SEQ * H_DIM * 2, stream);
  hipMemsetAsync(h1b, 0, (size_t)N_SEQ * H_DIM * 2, stream);
  hipMemsetAsync(cf, 0, (size_t)N_SEQ * H_DIM * 4, stream);
  hipMemsetAsync(cb, 0, (size_t)N_SEQ * H_DIM * 4, stream);

  k_lens<<<N_SEQ / 256, 256, 0, stream>>>(tok, lens);
  k_hist<<<N_SEQ / 256, 256, 0, stream>>>(lens, hist);
  k_offsets<<<1, 64, 0, stream>>>(hist, cursor, cnts);
  k_scatter<<<N_SEQ / 256, 256, 0, stream>>>(lens, cursor, perm, pinv, plens);
  k_embcvt<<<(V_SIZE * E_DIM) / 256, 256, 0, stream>>>(emb, embbf);
  k_wprep<<<(2 * 1024 * K_DIM) / 256, 256, 0, stream>>>(Wih_f, Whh_f, Wih_b, Whh_b, wptf, wptb);

  dim3 grid(512, 2);
  for (int s = 0; s < T_LEN; ++s) {
    const unsigned short* hrf = (s & 1) ? h1f : h0f;
    unsigned short* hwf       = (s & 1) ? h0f : h1f;
    const unsigned short* hrb = (s & 1) ? h1b : h0b;
    unsigned short* hwb       = (s & 1) ? h0b : h1b;
    k_step<<<grid, 512, 0, stream>>>(embbf, tok, perm, plens, cnts, wptf, wptb, b_f, b_b,
                                     hrf, hwf, hrb, hwb, cf, cb, s);
  }
  // after s=15 (odd), final h is in h0f / h0b (copy generations keep both buffers synced)
  k_pool<<<B_SAMP, 256, 0, stream>>>(h0f, h0b, pinv, plen, pooled);
  k_final<<<B_SAMP, 256, 0, stream>>>(pooled, Wlin, blin, out);
}